// Round 1
// baseline (10801.849 us; speedup 1.0000x reference)
//
#include <hip/hip_runtime.h>

// LSTM decoder (B=16,T=1024,CI=512,AR=256,H=1024,DO=80) for MI355X.
// R11 = R10 data path + 8-way-spread arrival counters. R10's barrier did ONE
// device-scope atomicAdd per WG on a single counter word -> 128 arrivals per
// epoch serialize at one IF$ bank (~1-2.5us/barrier). Now WG wl adds to
// counter line (wl&7) (8 lines, 128B apart); the poller issues all 8 loads
// as one pipelined burst (immediate offsets, single vmcnt round trip) and
// sums. Monotone-sum >= 128*epoch retains the same soundness argument.
//   WGs 0..127  = layer0: S1 (cell0, Whh0 LDS) -> S2 (LN+Wp0 LDS) -> za_all[t]
//   WGs 128..255= layer1: S3 (cell1, Wih1+Whh1 LDS) -> S4 (LN+Wp1 L2) -> zb, zs
// Cross-WG data: producers store sc0+sc1 (write-through to IF$), readers load
// plain cached AFTER the counter says all 128 arrivals of this epoch are in
// (write-once streams -> no stale-line hazard).

typedef unsigned short u16;
typedef short bf16x8 __attribute__((ext_vector_type(8)));
typedef float f32x4 __attribute__((ext_vector_type(4)));
typedef int i32x4 __attribute__((ext_vector_type(4)));

#define MFMA16(a, b, c) __builtin_amdgcn_mfma_f32_16x16x32_bf16((a), (b), (c), 0, 0, 0)

__device__ __forceinline__ u16 f2bf(float x) {
  unsigned u = __float_as_uint(x);
  return (u16)((u + 0x7fffu + ((u >> 16) & 1u)) >> 16);  // RNE
}
__device__ __forceinline__ float bf2f(u16 h) { return __uint_as_float(((unsigned)h) << 16); }
__device__ __forceinline__ float sigf(float x) { return 1.f / (1.f + __expf(-x)); }

__device__ __forceinline__ void gstore128(u16* p, i32x4 v) {
  asm volatile("global_store_dwordx4 %0, %1, off sc0 sc1" ::"v"((void*)p), "v"(v) : "memory");
}

// plain cached fragment loads: 8 x 16B at 64B stride (MFMA A-operand walk)
__device__ __forceinline__ void load8s(bf16x8 d[8], const u16* p) {
#pragma unroll
  for (int c = 0; c < 8; c++) d[c] = *(const bf16x8*)(p + (c << 5));
}

// one pipelined burst over the 8 counter lines (128B stride), single vmcnt
__device__ __forceinline__ int ld8sum(const int* base) {
  int v0, v1, v2, v3, v4, v5, v6, v7;
  asm volatile(
      "global_load_dword %0, %8, off sc0 sc1\n\t"
      "global_load_dword %1, %8, off offset:128 sc0 sc1\n\t"
      "global_load_dword %2, %8, off offset:256 sc0 sc1\n\t"
      "global_load_dword %3, %8, off offset:384 sc0 sc1\n\t"
      "global_load_dword %4, %8, off offset:512 sc0 sc1\n\t"
      "global_load_dword %5, %8, off offset:640 sc0 sc1\n\t"
      "global_load_dword %6, %8, off offset:768 sc0 sc1\n\t"
      "global_load_dword %7, %8, off offset:896 sc0 sc1\n\t"
      "s_waitcnt vmcnt(0)"
      : "=&v"(v0), "=&v"(v1), "=&v"(v2), "=&v"(v3), "=&v"(v4), "=&v"(v5), "=&v"(v6), "=&v"(v7)
      : "v"((const void*)base)
      : "memory");
  return v0 + v1 + v2 + v3 + v4 + v5 + v6 + v7;
}

// Arrival-counter barrier among 128 WGs. Monotone counters (8 lines); epoch e
// complete when sum >= 128*e. atomicAdd is device-scope (executes at the
// memory-side coherence point) and is issued only after vmcnt(0) drained this
// WG's sc0sc1 data stores -> counter observation implies data visibility.
__device__ __forceinline__ void cbar(int* ctr, int e, int tid, int slot) {
  asm volatile("s_waitcnt vmcnt(0)" ::: "memory");
  __syncthreads();
  if (tid == 0) {
    atomicAdd(ctr + (slot << 5), 1);  // own 128B line per slot
    const int target = e << 7;
    for (;;) {
      if (ld8sum(ctr) >= target) break;
      __builtin_amdgcn_s_sleep(2);
    }
  }
  __syncthreads();
}

// passive wait on another group's counters
__device__ __forceinline__ void wait_c(const int* ctr, int target, int tid) {
  if (tid == 0) {
    for (;;) {
      if (ld8sum(ctr) >= target) break;
      __builtin_amdgcn_s_sleep(2);
    }
  }
  __syncthreads();
}

// ---------------- prep kernels ----------------
__global__ __launch_bounds__(256) void cvt(const float* __restrict__ s, u16* __restrict__ d, int n) {
  int i = (blockIdx.x * 256 + threadIdx.x) * 4;
  if (i < n) {
    float4 v = *(const float4*)(s + i);
    unsigned lo = (unsigned)f2bf(v.x) | ((unsigned)f2bf(v.y) << 16);
    unsigned hi = (unsigned)f2bf(v.z) | ((unsigned)f2bf(v.w) << 16);
    *(uint2*)(d + i) = make_uint2(lo, hi);
  }
}

__global__ __launch_bounds__(256) void cvt_wpre1(const float* __restrict__ s, u16* __restrict__ d) {
  int i = blockIdx.x * 256 + threadIdx.x;  // < 256*96
  int r = i / 96, c = i - r * 96;
  d[i] = (c < 80) ? f2bf(s[r * 80 + c]) : (u16)0;
}

__global__ __launch_bounds__(256) void bsum(const float* __restrict__ a, const float* __restrict__ b,
                                            float* __restrict__ o) {
  int i = blockIdx.x * 256 + threadIdx.x;
  if (i < 4096) o[i] = a[i] + b[i];
}

__global__ __launch_bounds__(256) void pack_prev(const float* __restrict__ tg, const float* __restrict__ mean,
                                                 const float* __restrict__ scale, u16* __restrict__ prevp) {
  int i = blockIdx.x * 256 + threadIdx.x;  // < 16384*96
  int row = i / 96, c = i - row * 96;
  int t = row >> 4, b = row & 15;
  float v = 0.f;
  if (c < 80 && t > 0) v = (tg[((size_t)b * 1024 + (t - 1)) * 80 + c] - mean[c]) / scale[c];
  prevp[i] = f2bf(v);
}

__global__ __launch_bounds__(256) void pack_cond(const float* __restrict__ cond, u16* __restrict__ xall) {
  int i = (blockIdx.x * 256 + threadIdx.x) * 4;  // < 16384*512
  int row = i >> 9, c = i & 511;
  int t = row >> 4, b = row & 15;
  float4 v = *(const float4*)(cond + ((size_t)b * 1024 + t) * 512 + c);
  unsigned lo = (unsigned)f2bf(v.x) | ((unsigned)f2bf(v.y) << 16);
  unsigned hi = (unsigned)f2bf(v.z) | ((unsigned)f2bf(v.w) << 16);
  *(uint2*)(xall + (size_t)row * 768 + c) = make_uint2(lo, hi);
}

// ---------------- generic bf16 GEMM: C = act(A @ B^T + bias) ----------------
__global__ __launch_bounds__(256) void gemm_bt(const u16* __restrict__ A, int lda, const u16* __restrict__ B,
                                               int ldb, u16* __restrict__ C, int ldc,
                                               const float* __restrict__ bias, int K, int relu) {
  __shared__ u16 As[64 * 40];
  __shared__ u16 Bs[64 * 40];
  const int tid = threadIdx.x, lane = tid & 63, wv = tid >> 6;
  const int wr = wv >> 1, wc = wv & 1;
  const int m0 = blockIdx.x * 64, n0 = blockIdx.y * 64;
  const int lr = tid >> 2, lc = (tid & 3) * 8;
  f32x4 z = {0.f, 0.f, 0.f, 0.f};
  f32x4 acc[2][2] = {{z, z}, {z, z}};
  const u16* Ap = A + (size_t)(m0 + lr) * lda + lc;
  const u16* Bp = B + (size_t)(n0 + lr) * ldb + lc;
  for (int k0 = 0; k0 < K; k0 += 32) {
    int4 av = *(const int4*)(Ap + k0);
    int4 bv = *(const int4*)(Bp + k0);
    __syncthreads();
    *(int4*)(As + lr * 40 + lc) = av;
    *(int4*)(Bs + lr * 40 + lc) = bv;
    __syncthreads();
#pragma unroll
    for (int mi = 0; mi < 2; mi++) {
      bf16x8 af = *(const bf16x8*)(As + (wr * 32 + mi * 16 + (lane & 15)) * 40 + (lane >> 4) * 8);
#pragma unroll
      for (int ni = 0; ni < 2; ni++) {
        bf16x8 bf = *(const bf16x8*)(Bs + (wc * 32 + ni * 16 + (lane & 15)) * 40 + (lane >> 4) * 8);
        acc[mi][ni] = MFMA16(af, bf, acc[mi][ni]);
      }
    }
  }
#pragma unroll
  for (int mi = 0; mi < 2; mi++)
#pragma unroll
    for (int ni = 0; ni < 2; ni++) {
      int n = n0 + wc * 32 + ni * 16 + (lane & 15);
      float bs = bias ? bias[n] : 0.f;
#pragma unroll
      for (int r = 0; r < 4; r++) {
        int m = m0 + wr * 32 + mi * 16 + (lane >> 4) * 4 + r;
        float x = acc[mi][ni][r] + bs;
        if (relu) x = fmaxf(x, 0.f);
        C[(size_t)m * ldc + n] = f2bf(x);
      }
    }
}

// ---------------- final projection ----------------
__global__ __launch_bounds__(256) void out_proj(const u16* __restrict__ zs, const u16* __restrict__ Wb,
                                                const float* __restrict__ bout, float* __restrict__ out) {
  int wv = threadIdx.x >> 6, lane = threadIdx.x & 63;
  int tile = blockIdx.x * 4 + wv;  // 5120 tiles = 1024 m-tiles x 5 n-tiles
  int mt = tile / 5, nt = tile - mt * 5;
  int m0 = mt * 16, n0 = nt * 16;
  const u16* ap = zs + (size_t)(m0 + (lane & 15)) * 1024 + (lane >> 4) * 8;
  const u16* bp = Wb + (size_t)(n0 + (lane & 15)) * 1024 + (lane >> 4) * 8;
  f32x4 acc = {0.f, 0.f, 0.f, 0.f};
  for (int k = 0; k < 1024; k += 32) {
    bf16x8 a = *(const bf16x8*)(ap + k);
    bf16x8 b = *(const bf16x8*)(bp + k);
    acc = MFMA16(a, b, acc);
  }
  int n = n0 + (lane & 15);
  float bb = bout[n];
#pragma unroll
  for (int r = 0; r < 4; r++) {
    int m = m0 + (lane >> 4) * 4 + r;
    int t = m >> 4, b = m & 15;
    out[(size_t)b * 81920 + t * 80 + n] = acc[r] + bb;
  }
}

// ---------------- persistent recurrent kernel ----------------
struct RecP {
  const u16 *g0, *whh0b, *wih1b, *whh1b, *wp0b, *wp1b;
  const float *b1s, *bp0, *bp1, *lng0, *lnb0, *lng1, *lnb1;
  u16 *zs, *za_all, *hall;  // hall row t (131072B): h0 @u16+0, h1 @u16+16384, zb @u16+32768
  int *ctr0, *ctr1;         // per-group arrival counters (8 lines each, monotone)
};

#define SLICE 1032
#define OFF_PARTIAL 132096
#define OFF_GATES 140288
#define OFF_RED1 142336
#define OFF_RED2 143360
#define OFF_MUSIG 144384
#define OFF_C 144512
#define OFF_G0S 145024  // 512 u16 (4 gates x 16 b x 8 cols)
#define OFF_HT 146048   // 128 u16 pack tile
#define SMEM_BYTES 146304

__global__ __launch_bounds__(256, 1) void recurrent(RecP p) {
  extern __shared__ char smem[];
  u16* wA = (u16*)smem;       // l0: Whh0 slice (32 rows) | l1: Wih1 slice
  u16* wB = wA + 32 * SLICE;  // l0: Wp0 slice (16 rows, 8 real) | l1: Whh1 slice
  float* partial = (float*)(smem + OFF_PARTIAL);  // 2048 f
  float* gates2 = (float*)(smem + OFF_GATES);     // 512 f
  float* red1 = (float*)(smem + OFF_RED1);        // 256 f
  float* red2 = (float*)(smem + OFF_RED2);        // 256 f
  float* musig = (float*)(smem + OFF_MUSIG);      // 32 f
  float* cs = (float*)(smem + OFF_C);             // 128 f
  u16* g0s = (u16*)(smem + OFF_G0S);              // 512 u16
  u16* htile = (u16*)(smem + OFF_HT);             // 128 u16

  const int w = blockIdx.x, tid = threadIdx.x;
  const int lane = tid & 63, wv = tid >> 6;
  const int bl = lane & 15, q = lane >> 4;
  const bool grp0 = (w < 128);
  const int wl = grp0 ? w : (w - 128);
  const int slot = wl & 7;
  int* ctr = grp0 ? p.ctr0 : p.ctr1;

  // ---- stage weights (once). WG owns hidden cols 8*wl..8*wl+7.
  {
    int r = tid >> 3, kp = tid & 7;  // 32 rows, 8 threads/row
    int gN = (r >> 3) * 1024 + (wl << 3) + (r & 7);
    const u16* srcA = grp0 ? p.whh0b : p.wih1b;
#pragma unroll
    for (int i = 0; i < 16; i++) {
      int k = kp * 128 + i * 8;
      *(int4*)(wA + r * SLICE + k) = *(const int4*)(srcA + (size_t)gN * 1024 + k);
    }
    if (!grp0) {
#pragma unroll
      for (int i = 0; i < 16; i++) {
        int k = kp * 128 + i * 8;
        *(int4*)(wB + r * SLICE + k) = *(const int4*)(p.whh1b + (size_t)gN * 1024 + k);
      }
    } else {
      int r2 = tid >> 4, kp2 = tid & 15;  // 16 rows (8 real + 8 zero), 16 thr/row
      int4 z4 = make_int4(0, 0, 0, 0);
#pragma unroll
      for (int i = 0; i < 8; i++) {
        int k = kp2 * 64 + i * 8;
        int4 v = z4;
        if (r2 < 8) v = *(const int4*)(p.wp0b + (size_t)((wl << 3) + r2) * 1024 + k);
        *(int4*)(wB + r2 * SLICE + k) = v;
      }
    }
    if (tid < 128) cs[tid] = 0.f;
  }
  __syncthreads();

  // per-thread invariants
  const int nl0 = tid >> 4, be = tid & 15;
  const int gN0 = (nl0 >> 3) * 1024 + (wl << 3) + (nl0 & 7);
  const int gN1 = ((nl0 + 16) >> 3) * 1024 + (wl << 3) + ((nl0 + 16) & 7);
  const float bp0v = p.bp0[(wl << 3) + ((tid >> 4) & 7)];
  const float bp1v = p.bp1[(wl << 3) + ((tid >> 4) & 7)];
  const float b1a = p.b1s[gN0], b1b = p.b1s[gN1];
  // g0s read indices (gate group from nl0; col nl0&7; batch be)
  const int g0i0 = (((nl0 >> 3) << 4) + be) * 8 + (nl0 & 7);
  const int g0i1 = ((((nl0 >> 3) + 2) << 4) + be) * 8 + (nl0 & 7);

  if (grp0) {
    // ================= layer 0 =================
    i32x4 gcur = {0, 0, 0, 0}, gnext = {0, 0, 0, 0};
    if (tid < 64) {  // tile load: thread (g,b) -> 8 cols of gate-group g
      int g = tid >> 4, b = tid & 15;
      const u16* gp = p.g0 + (size_t)b * 4096 + g * 1024 + (wl << 3);
      asm volatile("global_load_dwordx4 %0, %1, off sc0 sc1\n\ts_waitcnt vmcnt(0)"
                   : "=&v"(gcur)
                   : "v"((const void*)gp)
                   : "memory");
    }

    for (int t = 0; t < 1024; ++t) {
      u16* hx0 = p.hall + (size_t)t * 65536;  // h0 stream row t

      // ---- S1: gates0 = G0[t] + za(t-1) @ Whh0^T ; cell0 -> h0
      if (t > 0) {
        const u16* zap = p.za_all + (size_t)(t - 1) * 16384 + bl * 1024 + (wv << 8) + (q << 3);
        bf16x8 av[8];
        load8s(av, zap);
        f32x4 acc0 = {0.f, 0.f, 0.f, 0.f}, acc1 = acc0;
#pragma unroll
        for (int c = 0; c < 8; c++) {
          int k = (wv << 8) + (c << 5) + (q << 3);
          acc0 = MFMA16(av[c], *(const bf16x8*)(wA + bl * SLICE + k), acc0);
          acc1 = MFMA16(av[c], *(const bf16x8*)(wA + (16 + bl) * SLICE + k), acc1);
        }
        *(f32x4*)(partial + (wv << 9) + (bl << 4) + (q << 2)) = acc0;
        *(f32x4*)(partial + (wv << 9) + ((16 + bl) << 4) + (q << 2)) = acc1;
      }
      if (tid < 64) *(i32x4*)(g0s + (tid << 3)) = gcur;  // distribute g0 tile
      if (t < 1023 && tid < 64) {                         // prefetch next (cbar's vmcnt drains)
        int g = tid >> 4, b = tid & 15;
        const u16* gp = p.g0 + (size_t)(((t + 1) << 4) | b) * 4096 + g * 1024 + (wl << 3);
        asm volatile("global_load_dwordx4 %0, %1, off sc0 sc1"
                     : "=&v"(gnext)
                     : "v"((const void*)gp)
                     : "memory");
      }
      __syncthreads();
      {
        float s0 = bf2f(g0s[g0i0]), s1 = bf2f(g0s[g0i1]);
        if (t > 0) {
          int e0 = tid, e1 = tid + 256;
          s0 += partial[e0] + partial[512 + e0] + partial[1024 + e0] + partial[1536 + e0];
          s1 += partial[e1] + partial[512 + e1] + partial[1024 + e1] + partial[1536 + e1];
        }
        gates2[tid] = s0;
        gates2[tid + 256] = s1;
      }
      __syncthreads();
      if (tid < 128) {
        int jj = tid >> 4, b = tid & 15;
        float xi = gates2[(jj)*16 + b];
        float xf = gates2[(8 + jj) * 16 + b];
        float xg = gates2[(16 + jj) * 16 + b];
        float xo = gates2[(24 + jj) * 16 + b];
        float c = cs[tid];
        float cn = sigf(xf) * c + sigf(xi) * tanhf(xg);
        cs[tid] = cn;
        htile[(b << 3) + jj] = f2bf(sigf(xo) * tanhf(cn));
      }
      __syncthreads();
      if (tid < 16) gstore128(hx0 + tid * 1024 + (wl << 3), *(const i32x4*)(htile + (tid << 3)));
      cbar(ctr, 2 * t + 1, tid, slot);

      // ---- S2: za(t) = tanh(LN(h0) @ Wp0^T + bp0)
      {
        bf16x8 dv[8];
        load8s(dv, hx0 + bl * 1024 + (wv << 8) + (q << 3));
        float sm = 0.f, sq = 0.f;
#pragma unroll
        for (int i = 0; i < 8; i++)
#pragma unroll
          for (int j = 0; j < 8; j++) {
            float x = bf2f((u16)dv[i][j]);
            sm += x;
            sq += x * x;
          }
        red1[(bl << 4) + (wv << 2) + q] = sm;  // dv fragments tile the full row per bl
        red2[(bl << 4) + (wv << 2) + q] = sq;
        __syncthreads();
        if (tid < 64) {
          int b2 = tid >> 2, g2 = tid & 3;
          float s = red1[b2 * 16 + g2 * 4] + red1[b2 * 16 + g2 * 4 + 1] + red1[b2 * 16 + g2 * 4 + 2] +
                    red1[b2 * 16 + g2 * 4 + 3];
          float qq = red2[b2 * 16 + g2 * 4] + red2[b2 * 16 + g2 * 4 + 1] + red2[b2 * 16 + g2 * 4 + 2] +
                     red2[b2 * 16 + g2 * 4 + 3];
          s += __shfl_xor(s, 1);
          s += __shfl_xor(s, 2);
          qq += __shfl_xor(qq, 1);
          qq += __shfl_xor(qq, 2);
          if (g2 == 0) {
            float mu = s * (1.f / 1024.f);
            float var = qq * (1.f / 1024.f) - mu * mu;
            musig[b2] = mu;
            musig[16 + b2] = rsqrtf(var + 1e-5f);
          }
        }
        __syncthreads();
        float mu = musig[bl], rs = musig[16 + bl];
        f32x4 acc = {0.f, 0.f, 0.f, 0.f};
#pragma unroll
        for (int c = 0; c < 8; c++) {
          int k = (wv << 8) + (c << 5) + (q << 3);
          float4 ga = *(const float4*)(p.lng0 + k);
          float4 gb = *(const float4*)(p.lng0 + k + 4);
          float4 ba = *(const float4*)(p.lnb0 + k);
          float4 bb = *(const float4*)(p.lnb0 + k + 4);
          bf16x8 a;
          a[0] = (short)f2bf((bf2f((u16)dv[c][0]) - mu) * rs * ga.x + ba.x);
          a[1] = (short)f2bf((bf2f((u16)dv[c][1]) - mu) * rs * ga.y + ba.y);
          a[2] = (short)f2bf((bf2f((u16)dv[c][2]) - mu) * rs * ga.z + ba.z);
          a[3] = (short)f2bf((bf2f((u16)dv[c][3]) - mu) * rs * ga.w + ba.w);
          a[4] = (short)f2bf((bf2f((u16)dv[c][4]) - mu) * rs * gb.x + bb.x);
          a[5] = (short)f2bf((bf2f((u16)dv[c][5]) - mu) * rs * gb.y + bb.y);
          a[6] = (short)f2bf((bf2f((u16)dv[c][6]) - mu) * rs * gb.z + bb.z);
          a[7] = (short)f2bf((bf2f((u16)dv[c][7]) - mu) * rs * gb.w + bb.w);
          acc = MFMA16(a, *(const bf16x8*)(wB + bl * SLICE + k), acc);
        }
        *(f32x4*)(partial + (wv << 8) + (bl << 4) + (q << 2)) = acc;
      }
      __syncthreads();
      if (tid < 128) {
        int nl = tid >> 4, b = tid & 15;
        float s = partial[nl * 16 + b] + partial[256 + nl * 16 + b] + partial[512 + nl * 16 + b] +
                  partial[768 + nl * 16 + b] + bp0v;
        htile[(b << 3) + nl] = f2bf(tanhf(s));
      }
      __syncthreads();
      if (tid < 16)
        gstore128(p.za_all + (size_t)t * 16384 + tid * 1024 + (wl << 3), *(const i32x4*)(htile + (tid << 3)));
      cbar(ctr, 2 * t + 2, tid, slot);
      gcur = gnext;
    }
  } else {
    // ================= layer 1 =================
    for (int t = 0; t < 1024; ++t) {
      u16* hx = p.hall + (size_t)t * 65536;       // h1 @u16+16384, zb @u16+32768
      wait_c(p.ctr0, (2 * t + 2) << 7, tid);      // za(t) published by layer0

      // ---- S3: gates1 = za(t) @ Wih1^T + zb(t-1) @ Whh1^T + b ; cell1 -> h1
      {
        const u16* zap = p.za_all + (size_t)t * 16384 + bl * 1024 + (wv << 8) + (q << 3);
        bf16x8 a1[8];
        load8s(a1, zap);
        f32x4 acc0 = {0.f, 0.f, 0.f, 0.f}, acc1 = acc0;
        if (t > 0) {
          const u16* zbp = p.hall + (size_t)(t - 1) * 65536 + 32768 + bl * 1024 + (wv << 8) + (q << 3);
          bf16x8 a2[8];
          load8s(a2, zbp);
#pragma unroll
          for (int c = 0; c < 8; c++) {
            int k = (wv << 8) + (c << 5) + (q << 3);
            acc0 = MFMA16(a1[c], *(const bf16x8*)(wA + bl * SLICE + k), acc0);
            acc1 = MFMA16(a1[c], *(const bf16x8*)(wA + (16 + bl) * SLICE + k), acc1);
            acc0 = MFMA16(a2[c], *(const bf16x8*)(wB + bl * SLICE + k), acc0);
            acc1 = MFMA16(a2[c], *(const bf16x8*)(wB + (16 + bl) * SLICE + k), acc1);
          }
        } else {
#pragma unroll
          for (int c = 0; c < 8; c++) {
            int k = (wv << 8) + (c << 5) + (q << 3);
            acc0 = MFMA16(a1[c], *(const bf16x8*)(wA + bl * SLICE + k), acc0);
            acc1 = MFMA16(a1[c], *(const bf16x8*)(wA + (16 + bl) * SLICE + k), acc1);
          }
        }
        *(f32x4*)(partial + (wv << 9) + (bl << 4) + (q << 2)) = acc0;
        *(f32x4*)(partial + (wv << 9) + ((16 + bl) << 4) + (q << 2)) = acc1;
      }
      __syncthreads();
      {
        int e0 = tid, e1 = tid + 256;
        float s0 = partial[e0] + partial[512 + e0] + partial[1024 + e0] + partial[1536 + e0] + b1a;
        float s1 = partial[e1] + partial[512 + e1] + partial[1024 + e1] + partial[1536 + e1] + b1b;
        gates2[e0] = s0;
        gates2[e1] = s1;
      }
      __syncthreads();
      if (tid < 128) {
        int jj = tid >> 4, b = tid & 15;
        float xi = gates2[(jj)*16 + b];
        float xf = gates2[(8 + jj) * 16 + b];
        float xg = gates2[(16 + jj) * 16 + b];
        float xo = gates2[(24 + jj) * 16 + b];
        float c = cs[tid];
        float cn = sigf(xf) * c + sigf(xi) * tanhf(xg);
        cs[tid] = cn;
        htile[(b << 3) + jj] = f2bf(sigf(xo) * tanhf(cn));
      }
      __syncthreads();
      if (tid < 16) gstore128(hx + 16384 + tid * 1024 + (wl << 3), *(const i32x4*)(htile + (tid << 3)));
      cbar(ctr, 2 * t + 1, tid, slot);

      // ---- S4: zb(t) = tanh(LN(h1) @ Wp1^T + bp1) ; zs[t] = zb
      {
        const u16* h1p = hx + 16384;
        bf16x8 dv[8];
        load8s(dv, h1p + bl * 1024 + (wv << 8) + (q << 3));
        float sm = 0.f, sq = 0.f;
#pragma unroll
        for (int i = 0; i < 8; i++)
#pragma unroll
          for (int j = 0; j < 8; j++) {
            float x = bf2f((u16)dv[i][j]);
            sm += x;
            sq += x * x;
          }
        red1[(bl << 4) + (wv << 2) + q] = sm;
        red2[(bl << 4) + (wv << 2) + q] = sq;
        __syncthreads();
        if (tid < 64) {
          int b2 = tid >> 2, g2 = tid & 3;
          float s = red1[b2 * 16 + g2 * 4] + red1[b2 * 16 + g2 * 4 + 1] + red1[b2 * 16 + g2 * 4 + 2] +
                    red1[b2 * 16 + g2 * 4 + 3];
          float qq = red2[b2 * 16 + g2 * 4] + red2[b2 * 16 + g2 * 4 + 1] + red2[b2 * 16 + g2 * 4 + 2] +
                     red2[b2 * 16 + g2 * 4 + 3];
          s += __shfl_xor(s, 1);
          s += __shfl_xor(s, 2);
          qq += __shfl_xor(qq, 1);
          qq += __shfl_xor(qq, 2);
          if (g2 == 0) {
            float mu = s * (1.f / 1024.f);
            float var = qq * (1.f / 1024.f) - mu * mu;
            musig[b2] = mu;
            musig[16 + b2] = rsqrtf(var + 1e-5f);
          }
        }
        __syncthreads();
        float mu = musig[bl], rs = musig[16 + bl];
        f32x4 acc = {0.f, 0.f, 0.f, 0.f};
        const u16* wpp = p.wp1b + (size_t)((wl << 3) + (bl & 7)) * 1024;  // plain loads, L2-hot
        bf16x8 z8 = {0, 0, 0, 0, 0, 0, 0, 0};
#pragma unroll
        for (int c = 0; c < 8; c++) {
          int k = (wv << 8) + (c << 5) + (q << 3);
          float4 ga = *(const float4*)(p.lng1 + k);
          float4 gb = *(const float4*)(p.lng1 + k + 4);
          float4 ba = *(const float4*)(p.lnb1 + k);
          float4 bb = *(const float4*)(p.lnb1 + k + 4);
          bf16x8 a;
          a[0] = (short)f2bf((bf2f((u16)dv[c][0]) - mu) * rs * ga.x + ba.x);
          a[1] = (short)f2bf((bf2f((u16)dv[c][1]) - mu) * rs * ga.y + ba.y);
          a[2] = (short)f2bf((bf2f((u16)dv[c][2]) - mu) * rs * ga.z + ba.z);
          a[3] = (short)f2bf((bf2f((u16)dv[c][3]) - mu) * rs * ga.w + ba.w);
          a[4] = (short)f2bf((bf2f((u16)dv[c][4]) - mu) * rs * gb.x + bb.x);
          a[5] = (short)f2bf((bf2f((u16)dv[c][5]) - mu) * rs * gb.y + bb.y);
          a[6] = (short)f2bf((bf2f((u16)dv[c][6]) - mu) * rs * gb.z + bb.z);
          a[7] = (short)f2bf((bf2f((u16)dv[c][7]) - mu) * rs * gb.w + bb.w);
          bf16x8 bw = *(const bf16x8*)(wpp + k);
          if (bl >= 8) bw = z8;
          acc = MFMA16(a, bw, acc);
        }
        *(f32x4*)(partial + (wv << 8) + (bl << 4) + (q << 2)) = acc;
      }
      __syncthreads();
      if (tid < 128) {
        int nl = tid >> 4, b = tid & 15;
        float s = partial[nl * 16 + b] + partial[256 + nl * 16 + b] + partial[512 + nl * 16 + b] +
                  partial[768 + nl * 16 + b] + bp1v;
        htile[(b << 3) + nl] = f2bf(tanhf(s));
      }
      __syncthreads();
      if (tid < 16) {
        i32x4 v = *(const i32x4*)(htile + (tid << 3));
        gstore128(hx + 32768 + tid * 1024 + (wl << 3), v);                  // zb stream row t
        *(i32x4*)(p.zs + (size_t)((t << 4) | tid) * 1024 + (wl << 3)) = v;  // plain: post-kernel
      }
      cbar(ctr, 2 * t + 2, tid, slot);
    }
  }
}

// ---------------- host ----------------
extern "C" void kernel_launch(void* const* d_in, const int* in_sizes, int n_in, void* d_out, int out_size,
                              void* d_ws, size_t ws_size, hipStream_t stream) {
  const float* cond = (const float*)d_in[0];
  const float* targets = (const float*)d_in[1];
  const float* tmean = (const float*)d_in[2];
  const float* tscale = (const float*)d_in[3];
  const float* Wpre1 = (const float*)d_in[4];
  const float* bpre1 = (const float*)d_in[5];
  const float* Wpre2 = (const float*)d_in[6];
  const float* bpre2 = (const float*)d_in[7];
  const float* Wih0 = (const float*)d_in[8];
  const float* Whh0 = (const float*)d_in[9];
  const float* bih0 = (const float*)d_in[10];
  const float* bhh0 = (const float*)d_in[11];
  const float* lng0 = (const float*)d_in[12];
  const float* lnb0 = (const float*)d_in[13];
  const float* Wp0 = (const float*)d_in[14];
  const float* bp0 = (const float*)d_in[15];
  const float* Wih1 = (const float*)d_in[16];
  const float* Whh1 = (const float*)d_in[17];
  const float* bih1 = (const float*)d_in[18];
  const float* bhh1 = (const float*)d_in[19];
  const float* lng1 = (const float*)d_in[20];
  const float* lnb1 = (const float*)d_in[21];
  const float* Wp1 = (const float*)d_in[22];
  const float* bp1 = (const float*)d_in[23];
  const float* Wout = (const float*)d_in[24];
  const float* bout = (const float*)d_in[25];

  char* ws = (char*)d_ws;
  int* ctr0 = (int*)(ws + 0);     // 8 counters, 128B apart (lines 0..7)
  int* ctr1 = (int*)(ws + 2048);  // 8 counters, 128B apart
  float* b0s = (float*)(ws + 102400);  // bih0+bhh0 (16KB)
  float* b1s = (float*)(ws + 118784);  // bih1+bhh1 (16KB)
  u16* woutb = (u16*)(ws + 135168);    // 160KB
  u16* wpre1b = (u16*)(ws + 299008);
  u16* wpre2b = (u16*)(ws + 348160);
  u16* wih0b = (u16*)(ws + 479232);
  u16* whh0b = (u16*)(ws + 6770688);
  u16* wih1b = (u16*)(ws + 15159296);
  u16* whh1b = (u16*)(ws + 23547904);
  u16* wp0b = (u16*)(ws + 31936512);
  u16* wp1b = (u16*)(ws + 34033664);
  u16* prevp = (u16*)(ws + 36130816);   // (T*B,96)  -- prep-only
  u16* hpre = (u16*)(ws + 39276544);    // (T*B,256) -- prep-only
  u16* xall = (u16*)(ws + 47665152);    // (T*B,768) -- prep-only
  u16* g0 = (u16*)(ws + 72830976);      // (T*B,4096)
  u16* zs = (u16*)(ws + 207048704);     // (T*B,1024)
  u16* za_all = (u16*)(ws + 36130816);  // 1024 x 32KB -- overlays prep buffers (dead by then)
  u16* hall = (u16*)(ws + 72699904);    // row t = g0 row t-1 (128KB, consumed at t-1)

  hipMemsetAsync(ws, 0, 4096, stream);  // counters

  cvt_wpre1<<<96, 256, 0, stream>>>(Wpre1, wpre1b);
  cvt<<<64, 256, 0, stream>>>(Wpre2, wpre2b, 65536);
  cvt<<<3072, 256, 0, stream>>>(Wih0, wih0b, 3145728);
  cvt<<<4096, 256, 0, stream>>>(Whh0, whh0b, 4194304);
  cvt<<<4096, 256, 0, stream>>>(Wih1, wih1b, 4194304);
  cvt<<<4096, 256, 0, stream>>>(Whh1, whh1b, 4194304);
  cvt<<<1024, 256, 0, stream>>>(Wp0, wp0b, 1048576);
  cvt<<<1024, 256, 0, stream>>>(Wp1, wp1b, 1048576);
  cvt<<<80, 256, 0, stream>>>(Wout, woutb, 81920);
  bsum<<<16, 256, 0, stream>>>(bih0, bhh0, b0s);
  bsum<<<16, 256, 0, stream>>>(bih1, bhh1, b1s);
  pack_prev<<<6144, 256, 0, stream>>>(targets, tmean, tscale, prevp);
  pack_cond<<<8192, 256, 0, stream>>>(cond, xall);

  gemm_bt<<<dim3(256, 4), 256, 0, stream>>>(prevp, 96, wpre1b, 96, hpre, 256, bpre1, 96, 1);
  gemm_bt<<<dim3(256, 4), 256, 0, stream>>>(hpre, 256, wpre2b, 256, xall + 512, 768, bpre2, 256, 1);
  gemm_bt<<<dim3(256, 64), 256, 0, stream>>>(xall, 768, wih0b, 768, g0, 4096, b0s, 768, 0);

  RecP rp;
  rp.g0 = g0;
  rp.whh0b = whh0b;
  rp.wih1b = wih1b;
  rp.whh1b = whh1b;
  rp.wp0b = wp0b;
  rp.wp1b = wp1b;
  rp.b1s = b1s;
  rp.bp0 = bp0;
  rp.bp1 = bp1;
  rp.lng0 = lng0;
  rp.lnb0 = lnb0;
  rp.lng1 = lng1;
  rp.lnb1 = lnb1;
  rp.zs = zs;
  rp.za_all = za_all;
  rp.hall = hall;
  rp.ctr0 = ctr0;
  rp.ctr1 = ctr1;

  hipFuncSetAttribute(reinterpret_cast<const void*>(recurrent), hipFuncAttributeMaxDynamicSharedMemorySize,
                      SMEM_BYTES);
  recurrent<<<dim3(256), dim3(256), SMEM_BYTES, stream>>>(rp);

  out_proj<<<1280, 256, 0, stream>>>(zs, woutb, bout, (float*)d_out);
}